// Round 1
// baseline (336.837 us; speedup 1.0000x reference)
//
#include <hip/hip_runtime.h>
#include <hip/hip_cooperative_groups.h>
#include <math.h>

namespace cg = cooperative_groups;

#define SEQ 65536
#define FEAT 512
#define NCH 256
#define CHUNK 256
#define THRES1 0.8f
#define THRES_UP 0.5f
#define NEGINF -1e30f

// ---- L1: a = sigmoid(h @ W + b) (one wave per row); blocks 0..255 also do
//          the per-chunk local scans; block 0 zeroes loss/cnt.
//          (UNCHANGED from the proven version.)
__global__ __launch_bounds__(256) void k_matvec_local(
        const float* __restrict__ h, const float* __restrict__ W,
        const float* __restrict__ b, const float* __restrict__ u_pred,
        const float* __restrict__ label,
        float* __restrict__ a,
        float* __restrict__ m_loc, int* __restrict__ openA,
        int* __restrict__ ltLoc, int* __restrict__ lfExcl,
        float* __restrict__ lastm, int* __restrict__ lastopen,
        int* __restrict__ lastgate, int* __restrict__ trigLast,
        int* __restrict__ fallLast, float* __restrict__ losscnt) {
    // ---- matvec part (all blocks) ----
    {
        int wave = threadIdx.x >> 6;
        int lane = threadIdx.x & 63;
        int row  = blockIdx.x * 4 + wave;
        const float4* hp = (const float4*)(h + (size_t)row * FEAT);
        const float4* wp = (const float4*)W;
        int base = lane * 2;  // each lane: elements [lane*8, lane*8+8)
        float4 h0 = hp[base], h1 = hp[base + 1];
        float4 w0 = wp[base], w1 = wp[base + 1];
        float s = h0.x * w0.x + h0.y * w0.y + h0.z * w0.z + h0.w * w0.w
                + h1.x * w1.x + h1.y * w1.y + h1.z * w1.z + h1.w * w1.w;
        #pragma unroll
        for (int off = 32; off; off >>= 1) s += __shfl_down(s, off, 64);
        if (lane == 0) a[row] = 1.0f / (1.0f + expf(-(s + b[0])));
    }
    if (blockIdx.x == 0 && threadIdx.x == 0) { losscnt[0] = 0.0f; losscnt[1] = 0.0f; }
    // ---- local scans (blocks 0..255 only; block-uniform branch) ----
    if (blockIdx.x < NCH) {
        __shared__ float su[256];
        __shared__ float sm[256];
        __shared__ int   sr[256];
        __shared__ int   st[256];
        __shared__ int   sf[256];
        int t = threadIdx.x, c = blockIdx.x;
        int i = c * CHUNK + t;
        float u = u_pred[i];
        su[t] = u;
        __syncthreads();
        bool gate = u >= THRES_UP;
        bool gprevLocal = (t > 0) && (su[t - 1] >= THRES_UP);
        bool gprev = (t > 0) ? gprevLocal : ((i > 0) && (u_pred[i - 1] >= THRES_UP));
        bool fall = gprev && !gate;
        bool trig = label[i] >= THRES1;

        sm[t] = gate ? u : NEGINF;                               // segmented run-max
        sr[t] = gate ? ((t > 0 && !gprevLocal) ? 1 : 0) : 1;     // boundary flag
        st[t] = trig ? i : -1;                                   // last trigger idx
        sf[t] = fall ? i : -1;                                   // last fall idx
        __syncthreads();
        for (int d = 1; d < 256; d <<= 1) {
            float lm = NEGINF; int lr = 0, lt = -1, lf = -1;
            bool act = t >= d;
            if (act) { lm = sm[t - d]; lr = sr[t - d]; lt = st[t - d]; lf = sf[t - d]; }
            __syncthreads();
            if (act) {
                if (!sr[t]) sm[t] = fmaxf(lm, sm[t]);
                sr[t] |= lr;
                st[t] = max(st[t], lt);
                sf[t] = max(sf[t], lf);
            }
            __syncthreads();
        }
        m_loc[i]  = sm[t];
        openA[i]  = (sr[t] == 0 && gate) ? 1 : 0;
        ltLoc[i]  = st[t];
        lfExcl[i] = (t == 0) ? -1 : sf[t - 1];
        if (t == 255) {
            lastm[c]    = sm[255];
            lastopen[c] = (sr[255] == 0 && gate) ? 1 : 0;
            lastgate[c] = gate ? 1 : 0;
            trigLast[c] = st[255];
            fallLast[c] = sf[255];
        }
    }
}

// ---- L2-4 fused (cooperative): up_hat finalize + alpha scan + y scan + loss,
//      with two grid.sync()s replacing the two kernel boundaries. Per-element
//      scan state (uh, Pc/Qc, Ec/Fc of own index) carried in registers; only
//      chunk summaries and the Ec/Fc arrays (needed at scattered j in the loss
//      stage) go through global memory.
__global__ __launch_bounds__(256) void k_fused_scan(
        const float* __restrict__ u_pred, const float* __restrict__ a,
        const float* __restrict__ m_loc, const int* __restrict__ openA,
        const float* __restrict__ lastm, const int* __restrict__ lastopen,
        const int* __restrict__ lastgate,
        const int* __restrict__ trigLast, const int* __restrict__ fallLast,
        const float* __restrict__ label, const float* __restrict__ thres2,
        const int* __restrict__ ltLoc, const int* __restrict__ lfExcl,
        float* __restrict__ EcG, float* __restrict__ FcG,
        float* __restrict__ Pch, float* __restrict__ Qch,
        float* __restrict__ Ech, float* __restrict__ Fch,
        float* __restrict__ out) {
    cg::grid_group grid = cg::this_grid();
    __shared__ float sc[256], sd[256], syIn[256];
    __shared__ int   st[256], sf[256];
    int t = threadIdx.x, c = blockIdx.x;
    int i = c * CHUNK + t;

    // ================= stage A (was k_uphat_alpha) =================
    // redundant max-plus scan over chunk summaries (each block computes all)
    {
        bool lg = lastgate[t] != 0;
        sc[t] = lg ? lastm[t] : NEGINF;                 // A
        sd[t] = (lg && lastopen[t]) ? 0.0f : NEGINF;    // B
    }
    __syncthreads();
    for (int d = 1; d < 256; d <<= 1) {
        float lA = NEGINF, lB = NEGINF;
        bool act = t >= d;
        if (act) { lA = sc[t - d]; lB = sd[t - d]; }
        __syncthreads();
        if (act) {
            float nA = fmaxf(sc[t], sd[t] + lA);   // max-plus compose right∘left
            float nB = fmaxf(sd[t] + lB, NEGINF);
            sc[t] = nA; sd[t] = nB;
        }
        __syncthreads();
    }
    float inc_c = (c == 0) ? NEGINF : sc[c - 1];
    __syncthreads();

    float u = u_pred[i];
    bool gate = u >= THRES_UP;
    float uh = gate ? (openA[i] ? fmaxf(m_loc[i], inc_c) : m_loc[i]) : u;
    out[3 * SEQ + i] = uh;   // up_hats
    out[2 * SEQ + i] = u;    // u_pred passthrough
    sc[t] = uh;
    sd[t] = (1.0f - uh) * a[i];
    __syncthreads();
    for (int d = 1; d < 256; d <<= 1) {
        float lc = 1.0f, ld = 0.0f;
        bool act = t >= d;
        if (act) { lc = sc[t - d]; ld = sd[t - d]; }
        __syncthreads();
        if (act) { sd[t] = sc[t] * ld + sd[t]; sc[t] = sc[t] * lc; }
        __syncthreads();
    }
    float PcR = sc[t], QcR = sd[t];          // stays in registers
    if (t == 255) { Pch[c] = PcR; Qch[c] = QcR; }
    __threadfence();
    grid.sync();

    // ================= stage B (was k_alpha_y) =================
    sc[t] = Pch[t]; sd[t] = Qch[t];
    __syncthreads();
    for (int d = 1; d < 256; d <<= 1) {
        float lc = 1.0f, ld = 0.0f;
        bool act = t >= d;
        if (act) { lc = sc[t - d]; ld = sd[t - d]; }
        __syncthreads();
        if (act) { sd[t] = sc[t] * ld + sd[t]; sc[t] = sc[t] * lc; }
        __syncthreads();
    }
    float alphaIn_c = (c == 0) ? 0.0f : sd[c - 1];
    __syncthreads();

    float al = PcR * alphaIn_c + QcR;
    out[SEQ + i] = al;  // alphas
    bool gateUh = uh >= THRES_UP;
    sc[t] = gateUh ? (1.0f - al) : 0.0f;
    sd[t] = gateUh ? al * uh : 0.0f;
    __syncthreads();
    for (int d = 1; d < 256; d <<= 1) {
        float lc = 1.0f, ld = 0.0f;
        bool act = t >= d;
        if (act) { lc = sc[t - d]; ld = sd[t - d]; }
        __syncthreads();
        if (act) { sd[t] = sc[t] * ld + sd[t]; sc[t] = sc[t] * lc; }
        __syncthreads();
    }
    float EcR = sc[t], FcR = sd[t];
    EcG[i] = EcR; FcG[i] = FcR;              // needed at scattered j below
    if (t == 255) { Ech[c] = EcR; Fch[c] = FcR; }
    __threadfence();
    grid.sync();

    // ================= stage C (was k_yfinal_loss) =================
    sc[t] = Ech[t]; sd[t] = Fch[t];
    st[t] = trigLast[t]; sf[t] = fallLast[t];
    __syncthreads();
    for (int d = 1; d < 256; d <<= 1) {
        float lc = 1.0f, ld = 0.0f; int lt = -1, lf = -1;
        bool act = t >= d;
        if (act) { lc = sc[t - d]; ld = sd[t - d]; lt = st[t - d]; lf = sf[t - d]; }
        __syncthreads();
        if (act) {
            sd[t] = sc[t] * ld + sd[t]; sc[t] = sc[t] * lc;
            st[t] = max(st[t], lt);
            sf[t] = max(sf[t], lf);
        }
        __syncthreads();
    }
    syIn[t] = (t == 0) ? 0.0f : sd[t - 1];   // incoming y for chunk t
    int trigIn_c = (c == 0) ? -1 : st[c - 1];
    int fallIn_c = (c == 0) ? -1 : sf[c - 1];
    __syncthreads();

    out[i] = EcR * syIn[c] + FcR;  // ys

    bool gprev = (i > 0) && (u_pred[i - 1] >= THRES_UP);
    bool fall = gprev && !gate;
    float contrib = 0.0f;
    int flag = 0;
    if (fall) {
        int j  = max(ltLoc[i], trigIn_c);    // last label-trigger <= i
        int pf = max(lfExcl[i], fallIn_c);   // last fall < i
        float lc = 0.0f;
        if (j > pf) {
            bool gj = u_pred[j] >= THRES_UP;
            float yj = EcG[j] * syIn[j >> 8] + FcG[j];
            float d = yj - label[j];
            lc = gj ? d * d : -1.0f;
        }
        bool isneg = (lc == -1.0f);
        bool nonzero = (lc != 0.0f);
        if (!isneg) {
            if (nonzero) { contrib = lc; flag = 1; }   // * R, R = 1.0
            else {
                int ip = i - 1;
                float ypre = EcG[ip] * syIn[ip >> 8] + FcG[ip];
                if (ypre >= THRES1) {
                    float t2 = thres2[(i < 59) ? i : 59];
                    float d2 = ypre - t2;
                    contrib = d2 * d2; flag = 1;
                }
            }
        }
    }
    #pragma unroll
    for (int off = 32; off; off >>= 1) {
        contrib += __shfl_down(contrib, off, 64);
        flag    += __shfl_down(flag, off, 64);
    }
    if ((t & 63) == 0 && (contrib != 0.0f || flag != 0)) {
        atomicAdd(&out[4 * SEQ], contrib);
        atomicAdd(&out[4 * SEQ + 1], (float)flag);
    }
}

extern "C" void kernel_launch(void* const* d_in, const int* in_sizes, int n_in,
                              void* d_out, int out_size, void* d_ws, size_t ws_size,
                              hipStream_t stream) {
    const float* h      = (const float*)d_in[0];
    const float* W      = (const float*)d_in[1];
    const float* b      = (const float*)d_in[2];
    const float* u_pred = (const float*)d_in[4];
    const float* label  = (const float*)d_in[5];
    const float* thres2 = (const float*)d_in[6];
    float* out  = (float*)d_out;
    float* base = (float*)d_ws;

    float* a      = base;
    float* m_loc  = base + SEQ;
    float* EcG    = base + 2 * (size_t)SEQ;   // was Pc (reused for y-pairs)
    float* FcG    = base + 3 * (size_t)SEQ;   // was Qc
    int*   openA  = (int*)(base + 4 * (size_t)SEQ);
    int*   ltLoc  = (int*)(base + 5 * (size_t)SEQ);
    int*   lfExcl = (int*)(base + 6 * (size_t)SEQ);
    float* sums   = base + 7 * (size_t)SEQ;
    float* lastm   = sums;
    float* Pch     = sums + NCH;
    float* Qch     = sums + 2 * NCH;
    float* Ech     = sums + 3 * NCH;
    float* Fch     = sums + 4 * NCH;
    int*   lastopen = (int*)(sums + 5 * NCH);
    int*   lastgate = (int*)(sums + 6 * NCH);
    int*   trigLast = (int*)(sums + 7 * NCH);
    int*   fallLast = (int*)(sums + 8 * NCH);

    k_matvec_local<<<SEQ / 4, 256, 0, stream>>>(h, W, b, u_pred, label, a,
                                                m_loc, openA, ltLoc, lfExcl,
                                                lastm, lastopen, lastgate, trigLast, fallLast,
                                                out + 4 * SEQ);

    void* args[] = {
        (void*)&u_pred, (void*)&a, (void*)&m_loc, (void*)&openA,
        (void*)&lastm, (void*)&lastopen, (void*)&lastgate,
        (void*)&trigLast, (void*)&fallLast,
        (void*)&label, (void*)&thres2,
        (void*)&ltLoc, (void*)&lfExcl,
        (void*)&EcG, (void*)&FcG,
        (void*)&Pch, (void*)&Qch, (void*)&Ech, (void*)&Fch,
        (void*)&out
    };
    hipLaunchCooperativeKernel((void*)k_fused_scan, dim3(NCH), dim3(CHUNK),
                               args, 0, stream);
}

// Round 2
// 237.235 us; speedup vs baseline: 1.4198x; 1.4198x over previous
//
#include <hip/hip_runtime.h>
#include <math.h>

#define SEQ 65536
#define FEAT 512
#define NCH 256
#define CHUNK 256
#define THRES1 0.8f
#define THRES_UP 0.5f
#define NEGINF -1e30f

// ---- L1: a = sigmoid(h @ W + b). Each wave handles 4 rows (8 float4 loads
//          in flight -> 4x memory-level parallelism vs previous 1-row/wave).
//          Blocks 0..255 also do the per-chunk local scans; block 0 zeroes
//          loss/cnt. Grid: SEQ / 16 = 4096 blocks.
__global__ __launch_bounds__(256) void k_matvec_local(
        const float* __restrict__ h, const float* __restrict__ W,
        const float* __restrict__ b, const float* __restrict__ u_pred,
        const float* __restrict__ label,
        float* __restrict__ a,
        float* __restrict__ m_loc, int* __restrict__ openA,
        int* __restrict__ ltLoc, int* __restrict__ lfExcl,
        float* __restrict__ lastm, int* __restrict__ lastopen,
        int* __restrict__ lastgate, int* __restrict__ trigLast,
        int* __restrict__ fallLast, float* __restrict__ losscnt) {
    // ---- matvec part (all blocks): 4 rows per wave ----
    {
        int wave = threadIdx.x >> 6;
        int lane = threadIdx.x & 63;
        int row0 = (blockIdx.x * 4 + wave) * 4;
        const float4* wp = (const float4*)W;
        int base = lane * 2;  // each lane: elements [lane*8, lane*8+8) of a row
        const float4* hp = (const float4*)(h + (size_t)row0 * FEAT);
        // issue all 8 row loads up-front (compiler batches them -> 8 dwordx4 in flight)
        float4 h00 = hp[base],       h01 = hp[base + 1];
        float4 h10 = hp[base + 128], h11 = hp[base + 129];
        float4 h20 = hp[base + 256], h21 = hp[base + 257];
        float4 h30 = hp[base + 384], h31 = hp[base + 385];
        float4 w0 = wp[base], w1 = wp[base + 1];
        float bb = b[0];
        float s0 = h00.x * w0.x + h00.y * w0.y + h00.z * w0.z + h00.w * w0.w
                 + h01.x * w1.x + h01.y * w1.y + h01.z * w1.z + h01.w * w1.w;
        float s1 = h10.x * w0.x + h10.y * w0.y + h10.z * w0.z + h10.w * w0.w
                 + h11.x * w1.x + h11.y * w1.y + h11.z * w1.z + h11.w * w1.w;
        float s2 = h20.x * w0.x + h20.y * w0.y + h20.z * w0.z + h20.w * w0.w
                 + h21.x * w1.x + h21.y * w1.y + h21.z * w1.z + h21.w * w1.w;
        float s3 = h30.x * w0.x + h30.y * w0.y + h30.z * w0.z + h30.w * w0.w
                 + h31.x * w1.x + h31.y * w1.y + h31.z * w1.z + h31.w * w1.w;
        #pragma unroll
        for (int off = 32; off; off >>= 1) {
            s0 += __shfl_down(s0, off, 64);
            s1 += __shfl_down(s1, off, 64);
            s2 += __shfl_down(s2, off, 64);
            s3 += __shfl_down(s3, off, 64);
        }
        if (lane == 0) {
            float4 r;
            r.x = 1.0f / (1.0f + expf(-(s0 + bb)));
            r.y = 1.0f / (1.0f + expf(-(s1 + bb)));
            r.z = 1.0f / (1.0f + expf(-(s2 + bb)));
            r.w = 1.0f / (1.0f + expf(-(s3 + bb)));
            *(float4*)(a + row0) = r;
        }
    }
    if (blockIdx.x == 0 && threadIdx.x == 0) { losscnt[0] = 0.0f; losscnt[1] = 0.0f; }
    // ---- local scans (blocks 0..255 only; block-uniform branch) ----
    if (blockIdx.x < NCH) {
        __shared__ float su[256];
        __shared__ float sm[256];
        __shared__ int   sr[256];
        __shared__ int   st[256];
        __shared__ int   sf[256];
        int t = threadIdx.x, c = blockIdx.x;
        int i = c * CHUNK + t;
        float u = u_pred[i];
        su[t] = u;
        __syncthreads();
        bool gate = u >= THRES_UP;
        bool gprevLocal = (t > 0) && (su[t - 1] >= THRES_UP);
        bool gprev = (t > 0) ? gprevLocal : ((i > 0) && (u_pred[i - 1] >= THRES_UP));
        bool fall = gprev && !gate;
        bool trig = label[i] >= THRES1;

        sm[t] = gate ? u : NEGINF;                               // segmented run-max
        sr[t] = gate ? ((t > 0 && !gprevLocal) ? 1 : 0) : 1;     // boundary flag
        st[t] = trig ? i : -1;                                   // last trigger idx
        sf[t] = fall ? i : -1;                                   // last fall idx
        __syncthreads();
        for (int d = 1; d < 256; d <<= 1) {
            float lm = NEGINF; int lr = 0, lt = -1, lf = -1;
            bool act = t >= d;
            if (act) { lm = sm[t - d]; lr = sr[t - d]; lt = st[t - d]; lf = sf[t - d]; }
            __syncthreads();
            if (act) {
                if (!sr[t]) sm[t] = fmaxf(lm, sm[t]);
                sr[t] |= lr;
                st[t] = max(st[t], lt);
                sf[t] = max(sf[t], lf);
            }
            __syncthreads();
        }
        m_loc[i]  = sm[t];
        openA[i]  = (sr[t] == 0 && gate) ? 1 : 0;
        ltLoc[i]  = st[t];
        lfExcl[i] = (t == 0) ? -1 : sf[t - 1];
        if (t == 255) {
            lastm[c]    = sm[255];
            lastopen[c] = (sr[255] == 0 && gate) ? 1 : 0;
            lastgate[c] = gate ? 1 : 0;
            trigLast[c] = st[255];
            fallLast[c] = sf[255];
        }
    }
}

// ---- L2: redundant cross-chunk max-plus scan -> inc_c; finalize up_hat;
//          per-chunk affine scan of alpha pairs ----
__global__ __launch_bounds__(256) void k_uphat_alpha(
        const float* __restrict__ u_pred, const float* __restrict__ a,
        const float* __restrict__ m_loc, const int* __restrict__ openA,
        const float* __restrict__ lastm, const int* __restrict__ lastopen,
        const int* __restrict__ lastgate,
        float* __restrict__ Pc, float* __restrict__ Qc,
        float* __restrict__ Pch, float* __restrict__ Qch,
        float* __restrict__ out) {
    __shared__ float sc[256], sd[256];
    int t = threadIdx.x, c = blockIdx.x;
    int i = c * CHUNK + t;

    // redundant max-plus scan over chunk summaries (each block computes all)
    {
        bool lg = lastgate[t] != 0;
        sc[t] = lg ? lastm[t] : NEGINF;                 // A
        sd[t] = (lg && lastopen[t]) ? 0.0f : NEGINF;    // B
    }
    __syncthreads();
    for (int d = 1; d < 256; d <<= 1) {
        float lA = NEGINF, lB = NEGINF;
        bool act = t >= d;
        if (act) { lA = sc[t - d]; lB = sd[t - d]; }
        __syncthreads();
        if (act) {
            float nA = fmaxf(sc[t], sd[t] + lA);   // max-plus compose right∘left
            float nB = fmaxf(sd[t] + lB, NEGINF);
            sc[t] = nA; sd[t] = nB;
        }
        __syncthreads();
    }
    float inc_c = (c == 0) ? NEGINF : sc[c - 1];
    __syncthreads();

    float u = u_pred[i];
    bool gate = u >= THRES_UP;
    float uh = gate ? (openA[i] ? fmaxf(m_loc[i], inc_c) : m_loc[i]) : u;
    out[3 * SEQ + i] = uh;   // up_hats
    out[2 * SEQ + i] = u;    // u_pred passthrough
    sc[t] = uh;
    sd[t] = (1.0f - uh) * a[i];
    __syncthreads();
    for (int d = 1; d < 256; d <<= 1) {
        float lc = 1.0f, ld = 0.0f;
        bool act = t >= d;
        if (act) { lc = sc[t - d]; ld = sd[t - d]; }
        __syncthreads();
        if (act) { sd[t] = sc[t] * ld + sd[t]; sc[t] = sc[t] * lc; }
        __syncthreads();
    }
    Pc[i] = sc[t];
    Qc[i] = sd[t];
    if (t == 255) { Pch[c] = sc[255]; Qch[c] = sd[255]; }
}

// ---- L3: redundant affine scan of Pch/Qch -> alphaIn_c; finalize alpha;
//          per-chunk affine scan of y pairs (into Pc/Qc as Ec/Fc) ----
__global__ __launch_bounds__(256) void k_alpha_y(
        float* __restrict__ Pc, float* __restrict__ Qc,
        const float* __restrict__ Pch, const float* __restrict__ Qch,
        float* __restrict__ out,
        float* __restrict__ Ech, float* __restrict__ Fch) {
    __shared__ float sc[256], sd[256];
    int t = threadIdx.x, c = blockIdx.x;
    int i = c * CHUNK + t;

    sc[t] = Pch[t]; sd[t] = Qch[t];
    __syncthreads();
    for (int d = 1; d < 256; d <<= 1) {
        float lc = 1.0f, ld = 0.0f;
        bool act = t >= d;
        if (act) { lc = sc[t - d]; ld = sd[t - d]; }
        __syncthreads();
        if (act) { sd[t] = sc[t] * ld + sd[t]; sc[t] = sc[t] * lc; }
        __syncthreads();
    }
    float alphaIn_c = (c == 0) ? 0.0f : sd[c - 1];
    __syncthreads();

    float al = Pc[i] * alphaIn_c + Qc[i];
    out[SEQ + i] = al;  // alphas
    float uh = out[3 * SEQ + i];
    bool gate = uh >= THRES_UP;
    sc[t] = gate ? (1.0f - al) : 0.0f;
    sd[t] = gate ? al * uh : 0.0f;
    __syncthreads();
    for (int d = 1; d < 256; d <<= 1) {
        float lc = 1.0f, ld = 0.0f;
        bool act = t >= d;
        if (act) { lc = sc[t - d]; ld = sd[t - d]; }
        __syncthreads();
        if (act) { sd[t] = sc[t] * ld + sd[t]; sc[t] = sc[t] * lc; }
        __syncthreads();
    }
    Pc[i] = sc[t];  // Ec
    Qc[i] = sd[t];  // Fc
    if (t == 255) { Ech[c] = sc[255]; Fch[c] = sd[255]; }
}

// ---- L4: redundant affine scan of Ech/Fch (full y-prefix in LDS) + redundant
//          max scans of trigLast/fallLast; finalize y; loss/cnt ----
__global__ __launch_bounds__(256) void k_yfinal_loss(
        const float* __restrict__ Ec, const float* __restrict__ Fc,
        const float* __restrict__ Ech, const float* __restrict__ Fch,
        const int* __restrict__ trigLast, const int* __restrict__ fallLast,
        const float* __restrict__ u_pred, const float* __restrict__ label,
        const float* __restrict__ thres2,
        const int* __restrict__ ltLoc, const int* __restrict__ lfExcl,
        float* __restrict__ out) {
    __shared__ float sc[256], sd[256], syIn[256];
    __shared__ int   st[256], sf[256];
    int t = threadIdx.x, c = blockIdx.x;
    int i = c * CHUNK + t;

    sc[t] = Ech[t]; sd[t] = Fch[t];
    st[t] = trigLast[t]; sf[t] = fallLast[t];
    __syncthreads();
    for (int d = 1; d < 256; d <<= 1) {
        float lc = 1.0f, ld = 0.0f; int lt = -1, lf = -1;
        bool act = t >= d;
        if (act) { lc = sc[t - d]; ld = sd[t - d]; lt = st[t - d]; lf = sf[t - d]; }
        __syncthreads();
        if (act) {
            sd[t] = sc[t] * ld + sd[t]; sc[t] = sc[t] * lc;
            st[t] = max(st[t], lt);
            sf[t] = max(sf[t], lf);
        }
        __syncthreads();
    }
    syIn[t] = (t == 0) ? 0.0f : sd[t - 1];   // incoming y for chunk t
    int trigIn_c = (c == 0) ? -1 : st[c - 1];
    int fallIn_c = (c == 0) ? -1 : sf[c - 1];
    __syncthreads();

    out[i] = Ec[i] * syIn[c] + Fc[i];  // ys

    float u = u_pred[i];
    bool gate = u >= THRES_UP;
    bool gprev = (i > 0) && (u_pred[i - 1] >= THRES_UP);
    bool fall = gprev && !gate;
    float contrib = 0.0f;
    int flag = 0;
    if (fall) {
        int j  = max(ltLoc[i], trigIn_c);    // last label-trigger <= i
        int pf = max(lfExcl[i], fallIn_c);   // last fall < i
        float lc = 0.0f;
        if (j > pf) {
            bool gj = u_pred[j] >= THRES_UP;
            float yj = Ec[j] * syIn[j >> 8] + Fc[j];
            float d = yj - label[j];
            lc = gj ? d * d : -1.0f;
        }
        bool isneg = (lc == -1.0f);
        bool nonzero = (lc != 0.0f);
        if (!isneg) {
            if (nonzero) { contrib = lc; flag = 1; }   // * R, R = 1.0
            else {
                int ip = i - 1;
                float ypre = Ec[ip] * syIn[ip >> 8] + Fc[ip];
                if (ypre >= THRES1) {
                    float t2 = thres2[(i < 59) ? i : 59];
                    float d2 = ypre - t2;
                    contrib = d2 * d2; flag = 1;
                }
            }
        }
    }
    #pragma unroll
    for (int off = 32; off; off >>= 1) {
        contrib += __shfl_down(contrib, off, 64);
        flag    += __shfl_down(flag, off, 64);
    }
    if ((t & 63) == 0 && (contrib != 0.0f || flag != 0)) {
        atomicAdd(&out[4 * SEQ], contrib);
        atomicAdd(&out[4 * SEQ + 1], (float)flag);
    }
}

extern "C" void kernel_launch(void* const* d_in, const int* in_sizes, int n_in,
                              void* d_out, int out_size, void* d_ws, size_t ws_size,
                              hipStream_t stream) {
    const float* h      = (const float*)d_in[0];
    const float* W      = (const float*)d_in[1];
    const float* b      = (const float*)d_in[2];
    const float* u_pred = (const float*)d_in[4];
    const float* label  = (const float*)d_in[5];
    const float* thres2 = (const float*)d_in[6];
    float* out  = (float*)d_out;
    float* base = (float*)d_ws;

    float* a      = base;
    float* m_loc  = base + SEQ;
    float* Pc     = base + 2 * (size_t)SEQ;
    float* Qc     = base + 3 * (size_t)SEQ;
    int*   openA  = (int*)(base + 4 * (size_t)SEQ);
    int*   ltLoc  = (int*)(base + 5 * (size_t)SEQ);
    int*   lfExcl = (int*)(base + 6 * (size_t)SEQ);
    float* sums   = base + 7 * (size_t)SEQ;
    float* lastm   = sums;
    float* Pch     = sums + NCH;
    float* Qch     = sums + 2 * NCH;
    float* Ech     = sums + 3 * NCH;
    float* Fch     = sums + 4 * NCH;
    int*   lastopen = (int*)(sums + 5 * NCH);
    int*   lastgate = (int*)(sums + 6 * NCH);
    int*   trigLast = (int*)(sums + 7 * NCH);
    int*   fallLast = (int*)(sums + 8 * NCH);

    k_matvec_local<<<SEQ / 16, 256, 0, stream>>>(h, W, b, u_pred, label, a,
                                                 m_loc, openA, ltLoc, lfExcl,
                                                 lastm, lastopen, lastgate, trigLast, fallLast,
                                                 out + 4 * SEQ);
    k_uphat_alpha<<<NCH, CHUNK, 0, stream>>>(u_pred, a, m_loc, openA,
                                             lastm, lastopen, lastgate,
                                             Pc, Qc, Pch, Qch, out);
    k_alpha_y<<<NCH, CHUNK, 0, stream>>>(Pc, Qc, Pch, Qch, out, Ech, Fch);
    k_yfinal_loss<<<NCH, CHUNK, 0, stream>>>(Pc, Qc, Ech, Fch, trigLast, fallLast,
                                             u_pred, label, thres2, ltLoc, lfExcl, out);
}